// Round 2
// baseline (101.395 us; speedup 1.0000x reference)
//
#include <hip/hip_runtime.h>

#define KCLS 21
#define HW (512 * 512)
#define BATCH 8
#define NBLK 2048
#define BLKSZ 256
#define NWAVE 4
#define BPI (NBLK / BATCH)        // 256 blocks per image
#define PIXB (HW / BPI)           // 1024 px per block
#define ITERS (PIXB / (BLKSZ * 2))// 2

// ws layout: u64 ti[8*21] | u32 aout[8*21] | f32 S[8*21] | u32 done

__global__ __launch_bounds__(BLKSZ, 5) void dicece_fused(
    const float* __restrict__ pr, const int* __restrict__ gt,
    unsigned long long* __restrict__ ws_ti, unsigned int* __restrict__ ws_aout,
    float* __restrict__ ws_S, unsigned int* __restrict__ ws_done,
    float* __restrict__ out)
{
    __shared__ unsigned long long s_gj[NWAVE][KCLS];  // packed: inter<<48 | tgt<<32 | S_fixed
    __shared__ unsigned int s_out[NWAVE][KCLS];
    __shared__ unsigned int s_last;
    const int t = threadIdx.x;
    const int w = t >> 6;
    if (t < NWAVE * KCLS) { (&s_gj[0][0])[t] = 0ull; (&s_out[0][0])[t] = 0u; }
    if (t == 0) s_last = 0u;
    __syncthreads();

    const int b = blockIdx.x / BPI;
    const int chunk = blockIdx.x - b * BPI;
    const int pix0 = chunk * PIXB;
    const float* __restrict__ pb = pr + (size_t)b * KCLS * HW;
    const int*   __restrict__ gb = gt + (size_t)b * HW;

    #pragma unroll 1
    for (int it = 0; it < ITERS; ++it) {
        const int pix = pix0 + (it * BLKSZ + t) * 2;

        float x[KCLS][2];
        #pragma unroll
        for (int k = 0; k < KCLS; ++k)
            *reinterpret_cast<float2*>(&x[k][0]) =
                *reinterpret_cast<const float2*>(pb + (size_t)k * HW + pix);
        int g[2];
        *reinterpret_cast<int2*>(&g[0]) = *reinterpret_cast<const int2*>(gb + pix);

        #pragma unroll
        for (int j = 0; j < 2; ++j) {
            float m = x[0][j]; int am = 0;
            #pragma unroll
            for (int k = 1; k < KCLS; ++k) if (x[k][j] > m) { m = x[k][j]; am = k; }
            float s = 0.f;
            #pragma unroll
            for (int k = 0; k < KCLS; ++k) s += __expf(x[k][j] - m);
            const int gj = g[j];
            float xg = x[0][j];
            #pragma unroll
            for (int k = 1; k < KCLS; ++k) xg = (k == gj) ? x[k][j] : xg;
            const float mag = (m - xg) + __logf(s);    // = -logp >= 0 always
            const unsigned int fx = (unsigned int)(mag * 65536.f + 0.5f);
            const unsigned long long pk =
                ((unsigned long long)(am == gj) << 48) | (1ull << 32) |
                (unsigned long long)fx;
            atomicAdd(&s_gj[w][gj], pk);     // inter+tgt+S in ONE atomic
            atomicAdd(&s_out[w][am], 1u);
        }
    }
    __syncthreads();

    // block flush: reduce 4 wave copies, 3 global atomics per class
    if (t < KCLS) {
        unsigned long long acc = 0ull; unsigned int ao = 0u;
        #pragma unroll
        for (int ww = 0; ww < NWAVE; ++ww) { acc += s_gj[ww][t]; ao += s_out[ww][t]; }
        const unsigned int fx  = (unsigned int)(acc & 0xFFFFFFFFull);
        const unsigned int tgt = (unsigned int)((acc >> 32) & 0xFFFFull);
        const unsigned int itr = (unsigned int)(acc >> 48);
        atomicAdd(&ws_ti[b * KCLS + t], ((unsigned long long)tgt << 32) | itr);
        atomicAdd(&ws_aout[b * KCLS + t], ao);
        atomicAdd(&ws_S[b * KCLS + t], (float)fx * (1.f / 65536.f));
    }
    __syncthreads();   // barrier drains all global atomics (vmcnt(0) before s_barrier)

    if (t == 0) {
        __threadfence();
        const unsigned int r = atomicAdd(ws_done, 1u);
        s_last = (r == NBLK - 1) ? 1u : 0u;
    }
    __syncthreads();
    if (s_last == 0u || t >= 64) return;

    // last block, first wave: finalize 168 bins -> scalar
    float wgt = 0.f, Nk = 0.f, Sk = 0.f;
    if (t < KCLS) {
        float dsum = 0.f; unsigned int nk = 0u;
        #pragma unroll
        for (int bb = 0; bb < BATCH; ++bb) {
            const unsigned long long ti = __hip_atomic_load(&ws_ti[bb * KCLS + t], __ATOMIC_RELAXED, __HIP_MEMORY_SCOPE_AGENT);
            const unsigned int ao       = __hip_atomic_load(&ws_aout[bb * KCLS + t], __ATOMIC_RELAXED, __HIP_MEMORY_SCOPE_AGENT);
            const float S               = __hip_atomic_load(&ws_S[bb * KCLS + t], __ATOMIC_RELAXED, __HIP_MEMORY_SCOPE_AGENT);
            const unsigned int itr = (unsigned int)(ti & 0xFFFFFFFFull);
            const unsigned int tgt = (unsigned int)(ti >> 32);
            nk += tgt;
            dsum += 2.f * (float)itr / ((float)ao + (float)tgt + 1e-10f);
            Sk += S;                         // = -sum logp over class t
        }
        wgt = 1.f - dsum * 0.125f;           // weight = 1 - dice_class
        Nk = (float)nk;
    }
    float num = wgt * Sk, den = wgt * Nk, wsum = wgt;
    #pragma unroll
    for (int off = 32; off > 0; off >>= 1) {
        num += __shfl_down(num, off);
        den += __shfl_down(den, off);
        wsum += __shfl_down(wsum, off);
    }
    // loss = mean(weight) + (sum w*(-logp)) / (sum w*N)
    if (t == 0) out[0] = wsum * (1.f / (float)KCLS) + num / den;
}

extern "C" void kernel_launch(void* const* d_in, const int* in_sizes, int n_in,
                              void* d_out, int out_size, void* d_ws, size_t ws_size,
                              hipStream_t stream) {
    const float* pr = (const float*)d_in[0];
    const int*   gt = (const int*)d_in[1];
    float* out = (float*)d_out;

    unsigned long long* ws_ti   = (unsigned long long*)d_ws;
    unsigned int*       ws_aout = (unsigned int*)(ws_ti + BATCH * KCLS);
    float*              ws_S    = (float*)(ws_aout + BATCH * KCLS);
    unsigned int*       ws_done = (unsigned int*)(ws_S + BATCH * KCLS);

    const size_t zbytes = (size_t)(BATCH * KCLS) * (8 + 4 + 4) + 4;
    hipMemsetAsync(d_ws, 0, zbytes, stream);
    dicece_fused<<<NBLK, BLKSZ, 0, stream>>>(pr, gt, ws_ti, ws_aout, ws_S, ws_done, out);
}